// Round 14
// baseline (54.059 us; speedup 1.0000x reference)
//
#include <hip/hip_runtime.h>
#include <stdint.h>

#define CLASS_NUM 7
#define QROWS 1050
#define QPAD  1152              // 72 groups * 16 rows; pad rows are zero
#define NPAD  102               // pad rows each add exp2(0)=1 to denom
#define NGRP  72
#define GPW   18                // groups per wave (one queue quarter)
#define QSUM_OFF (QPAD * 128)   // 147456: 7x128 fp32 class sums (after fp8 image)
#define C2L 2.8853900817779268f // 2/ln2 : exp(2s) = exp2(s*C2L)

typedef float f32x4 __attribute__((ext_vector_type(4)));
typedef long  long2v __attribute__((ext_vector_type(2)));

// raw v_exp_f32 via the modeled intrinsic (1 instr; ~1 ulp, R10 shows absmax<=0.094)
__device__ __forceinline__ float fexp2(float x) { return __builtin_amdgcn_exp2f(x); }

// pack 4 floats -> 4 fp8 e4m3 (OCP, RNE) in one dword
__device__ __forceinline__ unsigned pk8(float a, float b, float c, float d) {
  int v = __builtin_amdgcn_cvt_pk_fp8_f32(a, b, 0, false);
  v = __builtin_amdgcn_cvt_pk_fp8_f32(c, d, v, true);
  return (unsigned)v;
}

// ---- prep: (a) queue fp32 -> fp8 fragment-major image [g][lane][k];
// (b) per-class column sums via run-based atomics (qsum zeroed by memset).
__global__ __launch_bounds__(256) void prep_q8(
    const float* __restrict__ queue, char* __restrict__ ws)
{
  const int g = blockIdx.x, tid = threadIdx.x;
  {
    const int lane = tid >> 2, k = tid & 3;
    const int row = g * 16 + (lane & 15);
    const int col = k * 32 + (lane >> 4) * 8;
    uint2 u = {0u, 0u};
    if (row < QROWS) {
      const float4 v0 = *(const float4*)(queue + row * 128 + col);
      const float4 v1 = *(const float4*)(queue + row * 128 + col + 4);
      u.x = pk8(v0.x, v0.y, v0.z, v0.w);
      u.y = pk8(v1.x, v1.y, v1.z, v1.w);
    }
    *(uint2*)(ws + (size_t)g * 2048 + tid * 8) = u;
  }
  {
    float* qsum = (float*)(ws + QSUM_OFF);
    const int col = tid & 127;
    const int rbase = g * 16 + (tid >> 7) * 8;
    int c0 = -1; float s = 0.f;
#pragma unroll
    for (int rr = 0; rr < 8; ++rr) {
      const int row = rbase + rr;
      if (row < QROWS) {
        const int c = (row * 6991) >> 20;          // row/150, exact here
        if (c != c0) {
          if (c0 >= 0) atomicAdd(&qsum[c0 * 128 + col], s);
          c0 = c; s = 0.f;
        }
        s += queue[row * 128 + col];
      }
    }
    if (c0 >= 0) atomicAdd(&qsum[c0 * 128 + col], s);
  }
}

// ---- fused main: 2048 blocks x 256 thr (4 waves). Block owns 32 B-rows;
// wave w sweeps queue-quarter w. COMPG uses 4 INDEPENDENT 2-deep MFMA chains
// (halved critical path); unroll-by-3 rotation lets the scheduler interleave
// group g's exps with g+1's MFMAs.
__global__ __launch_bounds__(256, 2) void pgc_stream(
    const float* __restrict__ act, const float* __restrict__ ema,
    const float* __restrict__ plab, const char* __restrict__ ws,
    float* __restrict__ out)
{
  __shared__ __align__(16) char aT[4096];    // 32-row fp8 A tile, frag-major
  __shared__ float s_lpos[32], s_pd[32];
  __shared__ float dnp[4][32];

  const int tid = threadIdx.x, lane = tid & 63, wave = tid >> 6;
  const int lo = lane & 15, hi = lane >> 4;

  // ---- prologue: 8 threads/row. All independent loads issued up-front.
  {
    const int r = tid >> 3, j8 = tid & 7;
    const long grow = (long)blockIdx.x * 32 + r;
    const float* ap = act + grow * 128 + j8 * 16;
    const float* ep = ema + grow * 128 + j8 * 16;

    float pv = (j8 < CLASS_NUM) ? plab[grow * CLASS_NUM + j8] : -3.4e38f;
    f32x4 a4[4], e4[4];
#pragma unroll
    for (int u = 0; u < 4; ++u) a4[u] = *(const f32x4*)(ap + 4 * u);
#pragma unroll
    for (int u = 0; u < 4; ++u) e4[u] = *(const f32x4*)(ep + 4 * u);

    float a2 = 0.f, e2 = 0.f, ae = 0.f;
#pragma unroll
    for (int u = 0; u < 4; ++u) {
      a2 += a4[u].x*a4[u].x + a4[u].y*a4[u].y + a4[u].z*a4[u].z + a4[u].w*a4[u].w;
      e2 += e4[u].x*e4[u].x + e4[u].y*e4[u].y + e4[u].z*e4[u].z + e4[u].w*e4[u].w;
      ae += a4[u].x*e4[u].x + a4[u].y*e4[u].y + a4[u].z*e4[u].z + a4[u].w*e4[u].w;
    }
#pragma unroll
    for (int m = 1; m < 8; m <<= 1) {
      a2 += __shfl_xor(a2, m);
      e2 += __shfl_xor(e2, m);
      ae += __shfl_xor(ae, m);
    }
    const float rna = rsqrtf(a2), rne = rsqrtf(e2);

    // argmax over 7 classes via 8-lane vote (first-max tie rule)
    int bi = j8;
#pragma unroll
    for (int m = 1; m < 8; m <<= 1) {
      const float ov = __shfl_xor(pv, m);
      const int   oi = __shfl_xor(bi, m);
      if (ov > pv || (ov == pv && oi < bi)) { pv = ov; bi = oi; }
    }

    // positive-sum via precomputed class sums (fp32-exact)
    const float* qs = (const float*)(ws + QSUM_OFF) + bi * 128 + j8 * 16;
    float pdot = 0.f;
#pragma unroll
    for (int u = 0; u < 4; ++u) {
      const float4 qv = *(const float4*)(qs + 4 * u);
      pdot += a4[u].x*qv.x + a4[u].y*qv.y + a4[u].z*qv.z + a4[u].w*qv.w;
    }
#pragma unroll
    for (int m = 1; m < 8; m <<= 1) pdot += __shfl_xor(pdot, m);

    if (j8 == 0) {
      s_lpos[r] = ae * rna * rne * C2L;
      s_pd[r]   = pdot * rna;
    }

    // stage A frag-major: addr = s*2048 + (hi_*16 + lr)*32 + k*8   (s = r>>4)
    const float sc = rna * C2L;     // pre-scale so MFMA output is 2s/ln2
    const int s = r >> 4, lr = r & 15, k = j8 >> 1;
#pragma unroll
    for (int h2 = 0; h2 < 2; ++h2) {
      const int hi_ = (j8 & 1) * 2 + h2;
      const f32x4 x = a4[h2 * 2], y = a4[h2 * 2 + 1];
      uint2 u;
      u.x = pk8(x.x * sc, x.y * sc, x.z * sc, x.w * sc);
      u.y = pk8(y.x * sc, y.y * sc, y.z * sc, y.w * sc);
      *(uint2*)(aT + s * 2048 + (hi_ * 16 + lr) * 32 + k * 8) = u;
    }
  }
  __syncthreads();

  // A fragments (all 4 waves read the same 32 rows; LDS broadcast)
  const long2v la0 = *(const long2v*)(aT + lane * 32);
  const long2v la1 = *(const long2v*)(aT + lane * 32 + 16);
  const long2v lb0 = *(const long2v*)(aT + 2048 + lane * 32);
  const long2v lb1 = *(const long2v*)(aT + 2048 + lane * 32 + 16);

  float dn0[4] = {0.f, 0.f, 0.f, 0.f};
  float dn1[4] = {0.f, 0.f, 0.f, 0.f};
  const f32x4 Z = {0.f, 0.f, 0.f, 0.f};
  const char* qp = ws + (size_t)(wave * GPW) * 2048 + (size_t)lane * 32;

  long2v B0a, B0b, B1a, B1b, B2a, B2b;
#define LOADG(Xa, Xb, G)                                                \
  { Xa = *(const long2v*)(qp + (G) * 2048);                             \
    Xb = *(const long2v*)(qp + (G) * 2048 + 16); }
  // 4 independent 2-deep MFMA chains; one add joins each pair before exp.
#define COMPG(Xa, Xb)                                                   \
  { f32x4 c0 = Z, d0 = Z, c1 = Z, d1 = Z;                               \
    c0 = __builtin_amdgcn_mfma_f32_16x16x32_fp8_fp8(la0[0], Xa[0], c0, 0, 0, 0); \
    c1 = __builtin_amdgcn_mfma_f32_16x16x32_fp8_fp8(lb0[0], Xa[0], c1, 0, 0, 0); \
    d0 = __builtin_amdgcn_mfma_f32_16x16x32_fp8_fp8(la1[0], Xb[0], d0, 0, 0, 0); \
    d1 = __builtin_amdgcn_mfma_f32_16x16x32_fp8_fp8(lb1[0], Xb[0], d1, 0, 0, 0); \
    c0 = __builtin_amdgcn_mfma_f32_16x16x32_fp8_fp8(la0[1], Xa[1], c0, 0, 0, 0); \
    c1 = __builtin_amdgcn_mfma_f32_16x16x32_fp8_fp8(lb0[1], Xa[1], c1, 0, 0, 0); \
    d0 = __builtin_amdgcn_mfma_f32_16x16x32_fp8_fp8(la1[1], Xb[1], d0, 0, 0, 0); \
    d1 = __builtin_amdgcn_mfma_f32_16x16x32_fp8_fp8(lb1[1], Xb[1], d1, 0, 0, 0); \
    _Pragma("unroll")                                                   \
    for (int rg = 0; rg < 4; ++rg) {                                    \
      dn0[rg] += fexp2(c0[rg] + d0[rg]);                                \
      dn1[rg] += fexp2(c1[rg] + d1[rg]);                                \
    } }

  LOADG(B0a, B0b, 0)
  LOADG(B1a, B1b, 1)
  LOADG(B2a, B2b, 2)
#pragma unroll 1
  for (int g = 0; g < GPW - 3; g += 3) {
    COMPG(B0a, B0b) LOADG(B0a, B0b, g + 3)
    COMPG(B1a, B1b) LOADG(B1a, B1b, g + 4)
    COMPG(B2a, B2b) LOADG(B2a, B2b, g + 5)
  }
  COMPG(B0a, B0b)
  COMPG(B1a, B1b)
  COMPG(B2a, B2b)
#undef LOADG
#undef COMPG

  // reduce across the 16 q-column lanes of each row
#pragma unroll
  for (int rg = 0; rg < 4; ++rg)
#pragma unroll
    for (int m = 1; m < 16; m <<= 1) {
      dn0[rg] += __shfl_xor(dn0[rg], m);
      dn1[rg] += __shfl_xor(dn1[rg], m);
    }

  if (lo == 0) {
#pragma unroll
    for (int rg = 0; rg < 4; ++rg) {
      dnp[wave][hi * 4 + rg]      = dn0[rg];
      dnp[wave][16 + hi * 4 + rg] = dn1[rg];
    }
  }
  __syncthreads();

  // epilogue: thread i (< 32) owns block-row i
  if (tid < 32) {
    const int i = tid;
    const float dtot = dnp[0][i] + dnp[1][i] + dnp[2][i] + dnp[3][i];
    const float lp   = exp2f(s_lpos[i]);        // exp(2*<f,ema_f>)
    const float dnf  = lp + dtot - (float)NPAD;
    float loss = -logf(lp / dnf + 1e-8f) + 150.0f * logf(dnf) - 2.0f * s_pd[i];
#pragma unroll
    for (int m = 1; m < 32; m <<= 1) loss += __shfl_xor(loss, m);
    if (tid == 0)
      atomicAdd(out, loss * (1.0f / (151.0f * 65536.0f)));
  }
}

extern "C" void kernel_launch(void* const* d_in, const int* in_sizes, int n_in,
                              void* d_out, int out_size, void* d_ws, size_t ws_size,
                              hipStream_t stream) {
  const float* act   = (const float*)d_in[0];
  const float* ema   = (const float*)d_in[1];
  const float* plab  = (const float*)d_in[2];
  const float* queue = (const float*)d_in[3];
  float* out = (float*)d_out;

  hipMemsetAsync(d_out, 0, sizeof(float), stream);
  hipMemsetAsync((char*)d_ws + QSUM_OFF, 0, CLASS_NUM * 128 * sizeof(float), stream);

  prep_q8<<<dim3(NGRP), dim3(256), 0, stream>>>(queue, (char*)d_ws);

  pgc_stream<<<dim3(65536 / 32), dim3(256), 0, stream>>>(
      act, ema, plab, (const char*)d_ws, out);
}

// Round 16
// 44.368 us; speedup vs baseline: 1.2184x; 1.2184x over previous
//
#include <hip/hip_runtime.h>
#include <stdint.h>

#define CLASS_NUM 7
#define QROWS 1050
#define QPAD  1152              // 72 groups * 16 rows; pad rows are zero
#define NPAD  102               // pad rows each add exp2(0)=1 to denom
#define NGRP  72
#define GPW   18                // groups per wave (one queue quarter)
#define QSUM_OFF (QPAD * 128)   // 147456: 7x128 fp32 class sums (after fp8 image)
#define C2L 2.8853900817779268f // 2/ln2 : exp(2s) = exp2(s*C2L)

typedef float f32x4 __attribute__((ext_vector_type(4)));
typedef long  long2v __attribute__((ext_vector_type(2)));

__device__ __forceinline__ float fexp2(float x) { return __builtin_amdgcn_exp2f(x); }

// pack 4 floats -> 4 fp8 e4m3 (OCP, RNE) in one dword
__device__ __forceinline__ unsigned pk8(float a, float b, float c, float d) {
  int v = __builtin_amdgcn_cvt_pk_fp8_f32(a, b, 0, false);
  v = __builtin_amdgcn_cvt_pk_fp8_f32(c, d, v, true);
  return (unsigned)v;
}

// ---- prep (single dispatch): blocks 0-71 -> fp8 fragment-major queue image;
// blocks 72-78 -> per-class column sums (direct, no atomics, no memset);
// block 0 thread 0 also zeroes d_out (replays re-zero it each launch).
__global__ __launch_bounds__(256) void prep_q8(
    const float* __restrict__ queue, char* __restrict__ ws,
    float* __restrict__ out)
{
  const int b = blockIdx.x, tid = threadIdx.x;
  if (b == 0 && tid == 0) *out = 0.f;
  if (b < NGRP) {
    const int g = b;
    const int lane = tid >> 2, k = tid & 3;
    const int row = g * 16 + (lane & 15);
    const int col = k * 32 + (lane >> 4) * 8;
    uint2 u = {0u, 0u};
    if (row < QROWS) {
      const float4 v0 = *(const float4*)(queue + row * 128 + col);
      const float4 v1 = *(const float4*)(queue + row * 128 + col + 4);
      u.x = pk8(v0.x, v0.y, v0.z, v0.w);
      u.y = pk8(v1.x, v1.y, v1.z, v1.w);
    }
    *(uint2*)(ws + (size_t)g * 2048 + tid * 8) = u;
  } else if (tid < 128) {
    const int c = b - NGRP, d = tid;           // class c, column d
    float s = 0.f;
    const float* p = queue + c * 150 * 128 + d;
#pragma unroll 10
    for (int i = 0; i < 150; ++i) s += p[i * 128];
    ((float*)(ws + QSUM_OFF))[c * 128 + d] = s;
  }
}

// ---- fused main: 1024 blocks x 256 thr (4 waves). Block owns 64 B-rows;
// each wave holds ALL 4 A-frag sets (64 rows) and sweeps ONE queue-quarter.
// Halves L2 B-traffic vs 32-rows/wave; 16 MFMA + 16 exp per group gives
// enough per-group compute to cover L2 latency at depth-2 prefetch.
__global__ __launch_bounds__(256, 2) void pgc_stream(
    const float* __restrict__ act, const float* __restrict__ ema,
    const float* __restrict__ plab, const char* __restrict__ ws,
    float* __restrict__ out)
{
  __shared__ __align__(16) char aT[8192];    // 64-row fp8 A tile, frag-major
  __shared__ float s_lpos[64], s_pd[64];
  __shared__ float dnp[4][64];

  const int tid = threadIdx.x, lane = tid & 63, wave = tid >> 6;
  const int lo = lane & 15, hi = lane >> 4;

  // ---- prologue: 4 threads/row, 64 rows. All independent loads up-front.
  {
    const int r = tid >> 2, j4 = tid & 3;
    const long grow = (long)blockIdx.x * 64 + r;
    const float* ap = act + grow * 128 + j4 * 32;
    const float* ep = ema + grow * 128 + j4 * 32;

    float pv0 = plab[grow * CLASS_NUM + j4];
    float pv1 = (j4 + 4 < CLASS_NUM) ? plab[grow * CLASS_NUM + j4 + 4] : -3.4e38f;
    f32x4 a4[8], e4[8];
#pragma unroll
    for (int u = 0; u < 8; ++u) a4[u] = *(const f32x4*)(ap + 4 * u);
#pragma unroll
    for (int u = 0; u < 8; ++u) e4[u] = *(const f32x4*)(ep + 4 * u);

    float a2 = 0.f, e2 = 0.f, ae = 0.f;
#pragma unroll
    for (int u = 0; u < 8; ++u) {
      a2 += a4[u].x*a4[u].x + a4[u].y*a4[u].y + a4[u].z*a4[u].z + a4[u].w*a4[u].w;
      e2 += e4[u].x*e4[u].x + e4[u].y*e4[u].y + e4[u].z*e4[u].z + e4[u].w*e4[u].w;
      ae += a4[u].x*e4[u].x + a4[u].y*e4[u].y + a4[u].z*e4[u].z + a4[u].w*e4[u].w;
    }
#pragma unroll
    for (int m = 1; m < 4; m <<= 1) {
      a2 += __shfl_xor(a2, m);
      e2 += __shfl_xor(e2, m);
      ae += __shfl_xor(ae, m);
    }
    const float rna = rsqrtf(a2), rne = rsqrtf(e2);

    // argmax over 7 classes: 2 classes/thread then 4-lane first-max vote
    float pv = pv0; int bi = j4;
    if (pv1 > pv0) { pv = pv1; bi = j4 + 4; }
#pragma unroll
    for (int m = 1; m < 4; m <<= 1) {
      const float ov = __shfl_xor(pv, m);
      const int   oi = __shfl_xor(bi, m);
      if (ov > pv || (ov == pv && oi < bi)) { pv = ov; bi = oi; }
    }

    // positive-sum via precomputed class sums (fp32-exact)
    const float* qs = (const float*)(ws + QSUM_OFF) + bi * 128 + j4 * 32;
    float pdot = 0.f;
#pragma unroll
    for (int u = 0; u < 8; ++u) {
      const float4 qv = *(const float4*)(qs + 4 * u);
      pdot += a4[u].x*qv.x + a4[u].y*qv.y + a4[u].z*qv.z + a4[u].w*qv.w;
    }
#pragma unroll
    for (int m = 1; m < 4; m <<= 1) pdot += __shfl_xor(pdot, m);

    if (j4 == 0) {
      s_lpos[r] = ae * rna * rne * C2L;
      s_pd[r]   = pdot * rna;
    }

    // stage A frag-major: chunk ch = j4*4+cc (8 cols each); k=ch>>2=j4, hi_=cc
    // addr = (r>>4)*2048 + (hi_*16 + (r&15))*32 + k*8
    const float sc = rna * C2L;     // pre-scale so MFMA output is 2s/ln2
    const int st = r >> 4, lr = r & 15;
#pragma unroll
    for (int cc = 0; cc < 4; ++cc) {
      const f32x4 x = a4[cc * 2], y = a4[cc * 2 + 1];
      uint2 u;
      u.x = pk8(x.x * sc, x.y * sc, x.z * sc, x.w * sc);
      u.y = pk8(y.x * sc, y.y * sc, y.z * sc, y.w * sc);
      *(uint2*)(aT + st * 2048 + (cc * 16 + lr) * 32 + j4 * 8) = u;
    }
  }
  __syncthreads();

  // A fragments: all 4 sets (64 rows) per wave, LDS broadcast reads
  long2v sa[4][2];
#pragma unroll
  for (int s = 0; s < 4; ++s) {
    sa[s][0] = *(const long2v*)(aT + s * 2048 + lane * 32);
    sa[s][1] = *(const long2v*)(aT + s * 2048 + lane * 32 + 16);
  }

  float dn[4][4] = {{0.f,0.f,0.f,0.f},{0.f,0.f,0.f,0.f},
                    {0.f,0.f,0.f,0.f},{0.f,0.f,0.f,0.f}};
  const f32x4 Z = {0.f, 0.f, 0.f, 0.f};
  const char* qp = ws + (size_t)(wave * GPW) * 2048 + (size_t)lane * 32;

  long2v B0a, B0b, B1a, B1b;
#define LOADG(Xa, Xb, G)                                                \
  { Xa = *(const long2v*)(qp + (G) * 2048);                             \
    Xb = *(const long2v*)(qp + (G) * 2048 + 16); }
  // 4 independent 4-deep MFMA chains (one per A-set), 16 exp after.
#define COMPG(Xa, Xb)                                                   \
  { _Pragma("unroll")                                                   \
    for (int s = 0; s < 4; ++s) {                                       \
      f32x4 c = Z;                                                      \
      c = __builtin_amdgcn_mfma_f32_16x16x32_fp8_fp8(sa[s][0][0], Xa[0], c, 0, 0, 0); \
      c = __builtin_amdgcn_mfma_f32_16x16x32_fp8_fp8(sa[s][0][1], Xa[1], c, 0, 0, 0); \
      c = __builtin_amdgcn_mfma_f32_16x16x32_fp8_fp8(sa[s][1][0], Xb[0], c, 0, 0, 0); \
      c = __builtin_amdgcn_mfma_f32_16x16x32_fp8_fp8(sa[s][1][1], Xb[1], c, 0, 0, 0); \
      _Pragma("unroll")                                                 \
      for (int rg = 0; rg < 4; ++rg) dn[s][rg] += fexp2(c[rg]);         \
    } }

  LOADG(B0a, B0b, 0)
  LOADG(B1a, B1b, 1)
#pragma unroll 1
  for (int g = 0; g < GPW - 2; g += 2) {
    COMPG(B0a, B0b) LOADG(B0a, B0b, g + 2)
    COMPG(B1a, B1b) LOADG(B1a, B1b, g + 3)
  }
  COMPG(B0a, B0b)
  COMPG(B1a, B1b)
#undef LOADG
#undef COMPG

  // reduce across the 16 q-column lanes of each row
#pragma unroll
  for (int s = 0; s < 4; ++s)
#pragma unroll
    for (int rg = 0; rg < 4; ++rg)
#pragma unroll
      for (int m = 1; m < 16; m <<= 1)
        dn[s][rg] += __shfl_xor(dn[s][rg], m);

  if (lo == 0) {
#pragma unroll
    for (int s = 0; s < 4; ++s)
#pragma unroll
      for (int rg = 0; rg < 4; ++rg)
        dnp[wave][s * 16 + hi * 4 + rg] = dn[s][rg];
  }
  __syncthreads();

  // epilogue: thread i (< 64) owns block-row i
  if (tid < 64) {
    const int i = tid;
    const float dtot = dnp[0][i] + dnp[1][i] + dnp[2][i] + dnp[3][i];
    const float lp   = exp2f(s_lpos[i]);        // exp(2*<f,ema_f>)
    const float dnf  = lp + dtot - (float)NPAD;
    float loss = -logf(lp / dnf + 1e-8f) + 150.0f * logf(dnf) - 2.0f * s_pd[i];
#pragma unroll
    for (int m = 1; m < 64; m <<= 1) loss += __shfl_xor(loss, m);
    if (tid == 0)
      atomicAdd(out, loss * (1.0f / (151.0f * 65536.0f)));
  }
}

extern "C" void kernel_launch(void* const* d_in, const int* in_sizes, int n_in,
                              void* d_out, int out_size, void* d_ws, size_t ws_size,
                              hipStream_t stream) {
  const float* act   = (const float*)d_in[0];
  const float* ema   = (const float*)d_in[1];
  const float* plab  = (const float*)d_in[2];
  const float* queue = (const float*)d_in[3];
  float* out = (float*)d_out;

  prep_q8<<<dim3(NGRP + CLASS_NUM), dim3(256), 0, stream>>>(
      queue, (char*)d_ws, out);

  pgc_stream<<<dim3(65536 / 64), dim3(256), 0, stream>>>(
      act, ema, plab, (const char*)d_ws, out);
}

// Round 17
// 41.584 us; speedup vs baseline: 1.3000x; 1.0670x over previous
//
#include <hip/hip_runtime.h>
#include <stdint.h>

#define CLASS_NUM 7
#define QROWS 1050
#define QPAD  1152              // 72 groups * 16 rows; pad rows are zero
#define NPAD  102               // pad rows each add exp2(0)=1 to denom
#define NGRP  72
#define GPW   18                // groups per wave (one queue quarter)
#define QSUM_OFF (QPAD * 128)   // 147456: 7x128 fp32 class sums (after fp8 image)
#define PART_OFF 151552         // 1024 fp32 per-block partials
#define NBLK  1024
#define C2L 2.8853900817779268f // 2/ln2 : exp(2s) = exp2(s*C2L)

typedef float f32x4 __attribute__((ext_vector_type(4)));
typedef long  long2v __attribute__((ext_vector_type(2)));

__device__ __forceinline__ float fexp2(float x) { return __builtin_amdgcn_exp2f(x); }

// pack 4 floats -> 4 fp8 e4m3 (OCP, RNE) in one dword
__device__ __forceinline__ unsigned pk8(float a, float b, float c, float d) {
  int v = __builtin_amdgcn_cvt_pk_fp8_f32(a, b, 0, false);
  v = __builtin_amdgcn_cvt_pk_fp8_f32(c, d, v, true);
  return (unsigned)v;
}

// ---- prep (single dispatch): blocks 0-71 -> fp8 fragment-major queue image;
// blocks 72-78 -> per-class column sums (direct, no atomics, no memset).
__global__ __launch_bounds__(256) void prep_q8(
    const float* __restrict__ queue, char* __restrict__ ws)
{
  const int b = blockIdx.x, tid = threadIdx.x;
  if (b < NGRP) {
    const int g = b;
    const int lane = tid >> 2, k = tid & 3;
    const int row = g * 16 + (lane & 15);
    const int col = k * 32 + (lane >> 4) * 8;
    uint2 u = {0u, 0u};
    if (row < QROWS) {
      const float4 v0 = *(const float4*)(queue + row * 128 + col);
      const float4 v1 = *(const float4*)(queue + row * 128 + col + 4);
      u.x = pk8(v0.x, v0.y, v0.z, v0.w);
      u.y = pk8(v1.x, v1.y, v1.z, v1.w);
    }
    *(uint2*)(ws + (size_t)g * 2048 + tid * 8) = u;
  } else if (tid < 128) {
    const int c = b - NGRP, d = tid;           // class c, column d
    float s = 0.f;
    const float* p = queue + c * 150 * 128 + d;
#pragma unroll 10
    for (int i = 0; i < 150; ++i) s += p[i * 128];
    ((float*)(ws + QSUM_OFF))[c * 128 + d] = s;
  }
}

// ---- fused main: identical to R16 except the epilogue plain-stores the
// per-block partial (no same-line atomic burst; finalize kernel reduces).
__global__ __launch_bounds__(256, 2) void pgc_stream(
    const float* __restrict__ act, const float* __restrict__ ema,
    const float* __restrict__ plab, char* __restrict__ ws)
{
  __shared__ __align__(16) char aT[8192];    // 64-row fp8 A tile, frag-major
  __shared__ float s_lpos[64], s_pd[64];
  __shared__ float dnp[4][64];

  const int tid = threadIdx.x, lane = tid & 63, wave = tid >> 6;
  const int lo = lane & 15, hi = lane >> 4;

  // ---- prologue: 4 threads/row, 64 rows. All independent loads up-front.
  {
    const int r = tid >> 2, j4 = tid & 3;
    const long grow = (long)blockIdx.x * 64 + r;
    const float* ap = act + grow * 128 + j4 * 32;
    const float* ep = ema + grow * 128 + j4 * 32;

    float pv0 = plab[grow * CLASS_NUM + j4];
    float pv1 = (j4 + 4 < CLASS_NUM) ? plab[grow * CLASS_NUM + j4 + 4] : -3.4e38f;
    f32x4 a4[8], e4[8];
#pragma unroll
    for (int u = 0; u < 8; ++u) a4[u] = *(const f32x4*)(ap + 4 * u);
#pragma unroll
    for (int u = 0; u < 8; ++u) e4[u] = *(const f32x4*)(ep + 4 * u);

    float a2 = 0.f, e2 = 0.f, ae = 0.f;
#pragma unroll
    for (int u = 0; u < 8; ++u) {
      a2 += a4[u].x*a4[u].x + a4[u].y*a4[u].y + a4[u].z*a4[u].z + a4[u].w*a4[u].w;
      e2 += e4[u].x*e4[u].x + e4[u].y*e4[u].y + e4[u].z*e4[u].z + e4[u].w*e4[u].w;
      ae += a4[u].x*e4[u].x + a4[u].y*e4[u].y + a4[u].z*e4[u].z + a4[u].w*e4[u].w;
    }
#pragma unroll
    for (int m = 1; m < 4; m <<= 1) {
      a2 += __shfl_xor(a2, m);
      e2 += __shfl_xor(e2, m);
      ae += __shfl_xor(ae, m);
    }
    const float rna = rsqrtf(a2), rne = rsqrtf(e2);

    // argmax over 7 classes: 2 classes/thread then 4-lane first-max vote
    float pv = pv0; int bi = j4;
    if (pv1 > pv0) { pv = pv1; bi = j4 + 4; }
#pragma unroll
    for (int m = 1; m < 4; m <<= 1) {
      const float ov = __shfl_xor(pv, m);
      const int   oi = __shfl_xor(bi, m);
      if (ov > pv || (ov == pv && oi < bi)) { pv = ov; bi = oi; }
    }

    // positive-sum via precomputed class sums (fp32-exact)
    const float* qs = (const float*)(ws + QSUM_OFF) + bi * 128 + j4 * 32;
    float pdot = 0.f;
#pragma unroll
    for (int u = 0; u < 8; ++u) {
      const float4 qv = *(const float4*)(qs + 4 * u);
      pdot += a4[u].x*qv.x + a4[u].y*qv.y + a4[u].z*qv.z + a4[u].w*qv.w;
    }
#pragma unroll
    for (int m = 1; m < 4; m <<= 1) pdot += __shfl_xor(pdot, m);

    if (j4 == 0) {
      s_lpos[r] = ae * rna * rne * C2L;
      s_pd[r]   = pdot * rna;
    }

    // stage A frag-major: chunk ch = j4*4+cc (8 cols each); k=ch>>2=j4, hi_=cc
    // addr = (r>>4)*2048 + (hi_*16 + (r&15))*32 + k*8
    const float sc = rna * C2L;     // pre-scale so MFMA output is 2s/ln2
    const int st = r >> 4, lr = r & 15;
#pragma unroll
    for (int cc = 0; cc < 4; ++cc) {
      const f32x4 x = a4[cc * 2], y = a4[cc * 2 + 1];
      uint2 u;
      u.x = pk8(x.x * sc, x.y * sc, x.z * sc, x.w * sc);
      u.y = pk8(y.x * sc, y.y * sc, y.z * sc, y.w * sc);
      *(uint2*)(aT + st * 2048 + (cc * 16 + lr) * 32 + j4 * 8) = u;
    }
  }
  __syncthreads();

  // A fragments: all 4 sets (64 rows) per wave, LDS broadcast reads
  long2v sa[4][2];
#pragma unroll
  for (int s = 0; s < 4; ++s) {
    sa[s][0] = *(const long2v*)(aT + s * 2048 + lane * 32);
    sa[s][1] = *(const long2v*)(aT + s * 2048 + lane * 32 + 16);
  }

  float dn[4][4] = {{0.f,0.f,0.f,0.f},{0.f,0.f,0.f,0.f},
                    {0.f,0.f,0.f,0.f},{0.f,0.f,0.f,0.f}};
  const f32x4 Z = {0.f, 0.f, 0.f, 0.f};
  const char* qp = ws + (size_t)(wave * GPW) * 2048 + (size_t)lane * 32;

  long2v B0a, B0b, B1a, B1b;
#define LOADG(Xa, Xb, G)                                                \
  { Xa = *(const long2v*)(qp + (G) * 2048);                             \
    Xb = *(const long2v*)(qp + (G) * 2048 + 16); }
  // 4 independent 4-deep MFMA chains (one per A-set), 16 exp after.
#define COMPG(Xa, Xb)                                                   \
  { _Pragma("unroll")                                                   \
    for (int s = 0; s < 4; ++s) {                                       \
      f32x4 c = Z;                                                      \
      c = __builtin_amdgcn_mfma_f32_16x16x32_fp8_fp8(sa[s][0][0], Xa[0], c, 0, 0, 0); \
      c = __builtin_amdgcn_mfma_f32_16x16x32_fp8_fp8(sa[s][0][1], Xa[1], c, 0, 0, 0); \
      c = __builtin_amdgcn_mfma_f32_16x16x32_fp8_fp8(sa[s][1][0], Xb[0], c, 0, 0, 0); \
      c = __builtin_amdgcn_mfma_f32_16x16x32_fp8_fp8(sa[s][1][1], Xb[1], c, 0, 0, 0); \
      _Pragma("unroll")                                                 \
      for (int rg = 0; rg < 4; ++rg) dn[s][rg] += fexp2(c[rg]);         \
    } }

  LOADG(B0a, B0b, 0)
  LOADG(B1a, B1b, 1)
#pragma unroll 1
  for (int g = 0; g < GPW - 2; g += 2) {
    COMPG(B0a, B0b) LOADG(B0a, B0b, g + 2)
    COMPG(B1a, B1b) LOADG(B1a, B1b, g + 3)
  }
  COMPG(B0a, B0b)
  COMPG(B1a, B1b)
#undef LOADG
#undef COMPG

  // reduce across the 16 q-column lanes of each row
#pragma unroll
  for (int s = 0; s < 4; ++s)
#pragma unroll
    for (int rg = 0; rg < 4; ++rg)
#pragma unroll
      for (int m = 1; m < 16; m <<= 1)
        dn[s][rg] += __shfl_xor(dn[s][rg], m);

  if (lo == 0) {
#pragma unroll
    for (int s = 0; s < 4; ++s)
#pragma unroll
      for (int rg = 0; rg < 4; ++rg)
        dnp[wave][s * 16 + hi * 4 + rg] = dn[s][rg];
  }
  __syncthreads();

  // epilogue: thread i (< 64) owns block-row i; partial -> plain store
  if (tid < 64) {
    const int i = tid;
    const float dtot = dnp[0][i] + dnp[1][i] + dnp[2][i] + dnp[3][i];
    const float lp   = exp2f(s_lpos[i]);        // exp(2*<f,ema_f>)
    const float dnf  = lp + dtot - (float)NPAD;
    float loss = -logf(lp / dnf + 1e-8f) + 150.0f * logf(dnf) - 2.0f * s_pd[i];
#pragma unroll
    for (int m = 1; m < 64; m <<= 1) loss += __shfl_xor(loss, m);
    if (tid == 0)
      ((float*)(ws + PART_OFF))[blockIdx.x] = loss;   // no atomic
  }
}

// ---- finalize: one block sums the 1024 per-block partials.
__global__ __launch_bounds__(1024) void finalize(
    const char* __restrict__ ws, float* __restrict__ out)
{
  __shared__ float sred[16];
  const int tid = threadIdx.x;
  float v = ((const float*)(ws + PART_OFF))[tid];
#pragma unroll
  for (int m = 1; m < 64; m <<= 1) v += __shfl_xor(v, m);
  if ((tid & 63) == 0) sred[tid >> 6] = v;
  __syncthreads();
  if (tid < 16) {
    float s = sred[tid];
#pragma unroll
    for (int m = 1; m < 16; m <<= 1) s += __shfl_xor(s, m);
    if (tid == 0) *out = s * (1.0f / (151.0f * 65536.0f));
  }
}

extern "C" void kernel_launch(void* const* d_in, const int* in_sizes, int n_in,
                              void* d_out, int out_size, void* d_ws, size_t ws_size,
                              hipStream_t stream) {
  const float* act   = (const float*)d_in[0];
  const float* ema   = (const float*)d_in[1];
  const float* plab  = (const float*)d_in[2];
  const float* queue = (const float*)d_in[3];
  float* out = (float*)d_out;

  prep_q8<<<dim3(NGRP + CLASS_NUM), dim3(256), 0, stream>>>(queue, (char*)d_ws);

  pgc_stream<<<dim3(NBLK), dim3(256), 0, stream>>>(
      act, ema, plab, (char*)d_ws);

  finalize<<<dim3(1), dim3(1024), 0, stream>>>((const char*)d_ws, out);
}